// Round 7
// baseline (256.897 us; speedup 1.0000x reference)
//
#include <hip/hip_runtime.h>
#include <hip/hip_bf16.h>
#include <math.h>

// Problem constants (fixed shapes from setup_inputs)
#define NB    8
#define CIN   128
#define CO    32
#define CH    64          // 2*Co channels in qk
#define NN    65536       // H*W
#define CHUNKS 128        // gram partial chunks per batch (= waves per batch)
#define GXB   32          // gram blocks per batch (4 waves each -> 128 chunks)
#define SPW   (NN/CHUNKS) // 512 spatial columns per wave
#define SLABS (SPW/16)    // 32 K=16 MFMA slabs per wave

typedef __attribute__((ext_vector_type(8))) short bf16x8;
typedef __attribute__((ext_vector_type(16))) float f32x16;

__device__ __forceinline__ short f2bf(float f) {
    union { __hip_bfloat16 h; short s; } u;
    u.h = __float2bfloat16(f);
    return u.s;
}
__device__ __forceinline__ float bf2f(short s) {
    union { __hip_bfloat16 h; short s; } u;
    u.s = s;
    return __bfloat162float(u.h);
}

// ---------------------------------------------------------------------------
// Kernel A — EXACT R3 gram v2 (the 120 µs config): wave = one 512-col chunk,
// 32 slabs, unroll 4, no LDS; 32x32x16 bf16 MFMA hi/lo split.
// ---------------------------------------------------------------------------
__global__ __launch_bounds__(256) void gram_kernel(const float* __restrict__ qk,
                                                   float* __restrict__ part,
                                                   float* __restrict__ partsq) {
    const int b = blockIdx.y;
    const int w = threadIdx.x >> 6;
    const int l = threadIdx.x & 63;
    const int chunk = blockIdx.x * 4 + w;
    const int c = l & 31;       // channel (row for A / col for B)
    const int half = l >> 5;    // k-half selector

    const float* qrow = qk + (size_t)b * CH * NN + (size_t)(CO + c) * NN
                        + (size_t)chunk * SPW + half * 8;
    const float* krow = qk + (size_t)b * CH * NN + (size_t)c * NN
                        + (size_t)chunk * SPW + half * 8;

    f32x16 acc = {};
    float sqq = 0.f, sqk = 0.f;

#pragma unroll 4
    for (int s = 0; s < SLABS; ++s) {
        float4 q0 = *(const float4*)(qrow + s * 16);
        float4 q1 = *(const float4*)(qrow + s * 16 + 4);
        float4 k0 = *(const float4*)(krow + s * 16);
        float4 k1 = *(const float4*)(krow + s * 16 + 4);

        float qf[8] = {q0.x, q0.y, q0.z, q0.w, q1.x, q1.y, q1.z, q1.w};
        float kf[8] = {k0.x, k0.y, k0.z, k0.w, k1.x, k1.y, k1.z, k1.w};

        bf16x8 ah, al, bh, bl;
#pragma unroll
        for (int j = 0; j < 8; ++j) {
            short hq = f2bf(qf[j]);
            ah[j] = hq;
            al[j] = f2bf(qf[j] - bf2f(hq));
            short hk = f2bf(kf[j]);
            bh[j] = hk;
            bl[j] = f2bf(kf[j] - bf2f(hk));
            sqq = fmaf(qf[j], qf[j], sqq);   // square-sums in full f32
            sqk = fmaf(kf[j], kf[j], sqk);
        }
        acc = __builtin_amdgcn_mfma_f32_32x32x16_bf16(ah, bh, acc, 0, 0, 0);
        acc = __builtin_amdgcn_mfma_f32_32x32x16_bf16(ah, bl, acc, 0, 0, 0);
        acc = __builtin_amdgcn_mfma_f32_32x32x16_bf16(al, bh, acc, 0, 0, 0);
    }

    // combine the two k-halves' square-sum partials (channel = lane&31 on both)
    sqq += __shfl_xor(sqq, 32);
    sqk += __shfl_xor(sqk, 32);
    if (half == 0) {
        float* psq = partsq + ((size_t)b * CHUNKS + chunk) * 64;
        psq[c] = sqk;          // k channels 0..31
        psq[CO + c] = sqq;     // q channels 32..63
    }

    // C/D layout (m74/m101): col = lane&31, row = (r&3) + 8*(r>>2) + 4*(lane>>5)
    float* pp = part + ((size_t)b * CHUNKS + chunk) * 1024;
#pragma unroll
    for (int r = 0; r < 16; ++r) {
        int row = (r & 3) + 8 * (r >> 2) + 4 * half;   // q index
        pp[row * 32 + c] = acc[r];                     // col = k index
    }
}

// ---------------------------------------------------------------------------
// Kernel B1 — EXACT R3 reduce_kernel
// ---------------------------------------------------------------------------
__global__ __launch_bounds__(128) void reduce_kernel(const float* __restrict__ part,
                                                     const float* __restrict__ partsq,
                                                     float* __restrict__ Sred) {
    const int b = blockIdx.y;
    const int v = blockIdx.x * 64 + (threadIdx.x >> 1);
    const int h = threadIdx.x & 1;
    float s = 0.f;
    if (v < 1024) {
        const float* p = part + (size_t)b * CHUNKS * 1024 + v;
        for (int ch = h * (CHUNKS / 2); ch < (h + 1) * (CHUNKS / 2); ++ch)
            s += p[(size_t)ch * 1024];
    } else {
        const float* p = partsq + (size_t)b * CHUNKS * 64 + (v - 1024);
        for (int ch = h * (CHUNKS / 2); ch < (h + 1) * (CHUNKS / 2); ++ch)
            s += p[(size_t)ch * 64];
    }
    s += __shfl_xor(s, 1);
    if (h == 0) Sred[b * 1088 + v] = s;
}

// ---------------------------------------------------------------------------
// Kernel B2 — EXACT R3 attn_kernel
// ---------------------------------------------------------------------------
__global__ __launch_bounds__(256) void attn_kernel(const float* __restrict__ Sred,
                                                   const float* __restrict__ w_v,
                                                   const float* __restrict__ b_v,
                                                   const float* __restrict__ temp,
                                                   float* __restrict__ Weff,
                                                   float* __restrict__ beff) {
    __shared__ float sS[1024];
    __shared__ float snorm[64];
    __shared__ float sA[1024];
    const int t = threadIdx.x;
    const int b = blockIdx.x;

    for (int i = t; i < 1024; i += 256) sS[i] = Sred[b * 1088 + i];
    if (t < 64) snorm[t] = fmaxf(sqrtf(Sred[b * 1088 + 1024 + t]), 1e-12f);
    __syncthreads();

    if (t < 32) {
        const float T = temp[0];
        const float qn = snorm[32 + t];
        float m = -1e30f;
        for (int d = 0; d < 32; ++d)
            m = fmaxf(m, sS[t * 32 + d] / (qn * snorm[d]) * T);
        float sum = 0.f;
        for (int d = 0; d < 32; ++d)
            sum += expf(sS[t * 32 + d] / (qn * snorm[d]) * T - m);
        const float inv = 1.f / sum;
        for (int d = 0; d < 32; ++d)
            sA[t * 32 + d] = expf(sS[t * 32 + d] / (qn * snorm[d]) * T - m) * inv;
    }
    __syncthreads();

    for (int idx = t; idx < CO * CIN; idx += 256) {
        int cc = idx >> 7;
        int ci = idx & 127;
        float s = 0.f;
#pragma unroll
        for (int d = 0; d < 32; ++d) s += sA[cc * 32 + d] * w_v[d * CIN + ci];
        Weff[(size_t)b * CO * CIN + idx] = s;
    }
    if (t < 32) {
        float s = 0.f;
#pragma unroll
        for (int d = 0; d < 32; ++d) s += sA[t * 32 + d] * b_v[d];
        beff[b * CO + t] = s;
    }
}

// ---------------------------------------------------------------------------
// Kernel C — EXACT R3 out v1. Launched 3x this round for attribution:
// idempotent (output depends only on inputs), so total += 2*dur(out).
// ---------------------------------------------------------------------------
__global__ __launch_bounds__(256) void out_kernel(const float* __restrict__ x,
                                                  const float* __restrict__ Weff,
                                                  const float* __restrict__ beff,
                                                  float* __restrict__ out) {
    const int b = blockIdx.y;
    const int n0 = blockIdx.x * 512 + threadIdx.x * 2;
    const float* xb = x + (size_t)b * CIN * NN + n0;
    const float* Wb = Weff + (size_t)b * CO * CIN;
    const float* bb = beff + b * CO;

    float a0[CO], a1[CO];
#pragma unroll
    for (int o = 0; o < CO; ++o) { a0[o] = bb[o]; a1[o] = bb[o]; }

#pragma unroll 4
    for (int ci = 0; ci < CIN; ++ci) {
        float2 xv = *(const float2*)(xb + (size_t)ci * NN);
#pragma unroll
        for (int o = 0; o < CO; ++o) {
            float wv = Wb[o * CIN + ci];
            a0[o] = fmaf(wv, xv.x, a0[o]);
            a1[o] = fmaf(wv, xv.y, a1[o]);
        }
    }

    float* ob = out + (size_t)b * CO * NN + n0;
#pragma unroll
    for (int o = 0; o < CO; ++o) {
        float2 r;
        r.x = a0[o];
        r.y = a1[o];
        *(float2*)(ob + (size_t)o * NN) = r;
    }
}

// ---------------------------------------------------------------------------
extern "C" void kernel_launch(void* const* d_in, const int* in_sizes, int n_in,
                              void* d_out, int out_size, void* d_ws, size_t ws_size,
                              hipStream_t stream) {
    const float* x    = (const float*)d_in[0];
    const float* qk   = (const float*)d_in[1];
    const float* w_v  = (const float*)d_in[2];
    const float* b_v  = (const float*)d_in[3];
    const float* temp = (const float*)d_in[4];
    float* out = (float*)d_out;

    float* part   = (float*)d_ws;                       // NB*CHUNKS*1024 floats (4 MB)
    float* partsq = part + (size_t)NB * CHUNKS * 1024;  // NB*CHUNKS*64 floats (256 KB)
    float* Sred   = partsq + (size_t)NB * CHUNKS * 64;  // NB*1088 floats
    float* Weff   = Sred + (size_t)NB * 1088;           // NB*CO*CIN floats
    float* beff   = Weff + (size_t)NB * CO * CIN;       // NB*CO floats

    gram_kernel<<<dim3(GXB, NB), 256, 0, stream>>>(qk, part, partsq);
    reduce_kernel<<<dim3(17, NB), 128, 0, stream>>>(part, partsq, Sred);
    attn_kernel<<<dim3(NB), 256, 0, stream>>>(Sred, w_v, b_v, temp, Weff, beff);
    // --- attribution: out launched 3x (idempotent). dur_us = base + 2*dur(out).
    out_kernel<<<dim3(NN / 512, NB), 256, 0, stream>>>(x, Weff, beff, out);
    out_kernel<<<dim3(NN / 512, NB), 256, 0, stream>>>(x, Weff, beff, out);
    out_kernel<<<dim3(NN / 512, NB), 256, 0, stream>>>(x, Weff, beff, out);
}

// Round 8
// 121.326 us; speedup vs baseline: 2.1174x; 2.1174x over previous
//
#include <hip/hip_runtime.h>
#include <hip/hip_bf16.h>
#include <math.h>

// Problem constants (fixed shapes from setup_inputs)
#define NB    8
#define CIN   128
#define CO    32
#define CH    64            // 2*Co channels in qk
#define NN    65536         // H*W
#define CPB   1024          // columns per gram block
#define GBLK  (NN/CPB)      // 64 gram blocks per batch
#define TCOLS 128           // columns per LDS tile
#define NTILES (CPB/TCOLS)  // 8 tiles per block

typedef __attribute__((ext_vector_type(8))) short bf16x8;
typedef __attribute__((ext_vector_type(16))) float f32x16;

__device__ __forceinline__ short f2bf(float f) {
    union { __hip_bfloat16 h; short s; } u;
    u.h = __float2bfloat16(f);
    return u.s;
}
__device__ __forceinline__ float bf2f(short s) {
    union { __hip_bfloat16 h; short s; } u;
    u.s = s;
    return __bfloat162float(u.h);
}

// ---------------------------------------------------------------------------
// Kernel A v5 — coalesced global -> XOR-swizzled LDS -> MFMA.
// Block = 1024 cols (8 tiles of 128). Load phase: lane = spatial (coalesced
// 1KB/instr). LDS tile [64ch][32 float4] with f ^= row&7 swizzle (involution;
// store conflict-free, fragment read at b128 wave64 bank minimum).
// Wave w computes k-sub-slices {2w, 2w+1} per tile; 32x32x16 bf16 MFMA hi/lo
// split (err ~2^-18). Square-sums accumulated in the load phase.
//   part[b][blk][q*32+k], partsq[b][blk][ch] (0..31=k, 32..63=q)
// ---------------------------------------------------------------------------
__global__ __launch_bounds__(256) void gram_kernel(const float* __restrict__ qk,
                                                   float* __restrict__ part,
                                                   float* __restrict__ partsq) {
    __shared__ float smem[CH * TCOLS];   // 8192 floats = 32 KB; reused for reduce
    float4* tile4 = (float4*)smem;       // [64][32] float4 view

    const int b = blockIdx.y;
    const int blk = blockIdx.x;
    const int t = threadIdx.x;
    const int w = t >> 6;
    const int l = t & 63;
    const int c = l & 31;       // channel within the 32-set
    const int half = l >> 5;    // k-half selector (col offset 8)

    const float* qkb = qk + (size_t)b * CH * NN;
    const size_t colbase0 = (size_t)blk * CPB;

    f32x16 acc = {};
    float sq[8] = {0.f, 0.f, 0.f, 0.f, 0.f, 0.f, 0.f, 0.f};

    for (int tau = 0; tau < NTILES; ++tau) {
        const size_t colbase = colbase0 + (size_t)tau * TCOLS;
        __syncthreads();   // previous tile's LDS reads complete
        // ---- load: thread t, step k: flat = t + k*256; row = flat>>5 (channel),
        //      col4 = flat&31 (spatial/4). Lanes consecutive col4 -> coalesced.
#pragma unroll
        for (int k = 0; k < 8; ++k) {
            int flat = t + k * 256;
            int row = flat >> 5;
            int col4 = flat & 31;
            float4 v = *(const float4*)(qkb + (size_t)row * NN + colbase + col4 * 4);
            sq[k] = fmaf(v.x, v.x, sq[k]);
            sq[k] = fmaf(v.y, v.y, sq[k]);
            sq[k] = fmaf(v.z, v.z, sq[k]);
            sq[k] = fmaf(v.w, v.w, sq[k]);
            tile4[row * 32 + (col4 ^ (row & 7))] = v;
        }
        __syncthreads();
        // ---- compute: wave w -> sub-slices s = 2w, 2w+1 (16 cols each)
#pragma unroll
        for (int ss = 0; ss < 2; ++ss) {
            const int s = 2 * w + ss;
            const int f0 = s * 4 + half * 2;
            const int qrow = CO + c;
            const int krow = c;
            const int sw = c & 7;    // (32+c)&7 == c&7
            float4 q0 = tile4[qrow * 32 + (f0 ^ sw)];
            float4 q1 = tile4[qrow * 32 + ((f0 + 1) ^ sw)];
            float4 k0 = tile4[krow * 32 + (f0 ^ sw)];
            float4 k1 = tile4[krow * 32 + ((f0 + 1) ^ sw)];

            float qf[8] = {q0.x, q0.y, q0.z, q0.w, q1.x, q1.y, q1.z, q1.w};
            float kf[8] = {k0.x, k0.y, k0.z, k0.w, k1.x, k1.y, k1.z, k1.w};

            bf16x8 ah, al, bh, bl;
#pragma unroll
            for (int j = 0; j < 8; ++j) {
                short hq = f2bf(qf[j]);
                ah[j] = hq;
                al[j] = f2bf(qf[j] - bf2f(hq));
                short hk = f2bf(kf[j]);
                bh[j] = hk;
                bl[j] = f2bf(kf[j] - bf2f(hk));
            }
            acc = __builtin_amdgcn_mfma_f32_32x32x16_bf16(ah, bh, acc, 0, 0, 0);
            acc = __builtin_amdgcn_mfma_f32_32x32x16_bf16(ah, bl, acc, 0, 0, 0);
            acc = __builtin_amdgcn_mfma_f32_32x32x16_bf16(al, bh, acc, 0, 0, 0);
        }
    }
    __syncthreads();   // all tile reads done; smem is now free for reduction

    // ---- stage per-wave acc: C/D layout col = lane&31 (k idx),
    //      row = (r&3) + 8*(r>>2) + 4*half (q idx)
#pragma unroll
    for (int r = 0; r < 16; ++r) {
        int row = (r & 3) + 8 * (r >> 2) + 4 * half;
        smem[w * 1024 + row * 32 + c] = acc[r];
    }
    // ---- stage per-thread square-sums: row = (t>>5)+8k, slot = t&31
#pragma unroll
    for (int k = 0; k < 8; ++k)
        smem[4096 + ((t >> 5) + 8 * k) * 32 + (t & 31)] = sq[k];
    __syncthreads();

    float* pp = part + ((size_t)b * GBLK + blk) * 1024;
#pragma unroll
    for (int j = 0; j < 4; ++j) {
        int idx = t + j * 256;
        pp[idx] = smem[idx] + smem[1024 + idx] + smem[2048 + idx] + smem[3072 + idx];
    }
    if (t < 64) {
        float s = 0.f;
#pragma unroll
        for (int i = 0; i < 32; ++i) s += smem[4096 + t * 32 + i];
        partsq[((size_t)b * GBLK + blk) * 64 + t] = s;
    }
}

// ---------------------------------------------------------------------------
// Kernel B1: reduce partials over 64 chunks -> Sred[b][0..1023]=S, [1024..1087]=sumsq
// ---------------------------------------------------------------------------
__global__ __launch_bounds__(128) void reduce_kernel(const float* __restrict__ part,
                                                     const float* __restrict__ partsq,
                                                     float* __restrict__ Sred) {
    const int b = blockIdx.y;
    const int v = blockIdx.x * 64 + (threadIdx.x >> 1);
    const int h = threadIdx.x & 1;
    float s = 0.f;
    if (v < 1024) {
        const float* p = part + (size_t)b * GBLK * 1024 + v;
        for (int ch = h * (GBLK / 2); ch < (h + 1) * (GBLK / 2); ++ch)
            s += p[(size_t)ch * 1024];
    } else {
        const float* p = partsq + (size_t)b * GBLK * 64 + (v - 1024);
        for (int ch = h * (GBLK / 2); ch < (h + 1) * (GBLK / 2); ++ch)
            s += p[(size_t)ch * 64];
    }
    s += __shfl_xor(s, 1);
    if (h == 0) Sred[b * 1088 + v] = s;
}

// ---------------------------------------------------------------------------
// Kernel B2 — EXACT R3 attn_kernel
// ---------------------------------------------------------------------------
__global__ __launch_bounds__(256) void attn_kernel(const float* __restrict__ Sred,
                                                   const float* __restrict__ w_v,
                                                   const float* __restrict__ b_v,
                                                   const float* __restrict__ temp,
                                                   float* __restrict__ Weff,
                                                   float* __restrict__ beff) {
    __shared__ float sS[1024];
    __shared__ float snorm[64];
    __shared__ float sA[1024];
    const int t = threadIdx.x;
    const int b = blockIdx.x;

    for (int i = t; i < 1024; i += 256) sS[i] = Sred[b * 1088 + i];
    if (t < 64) snorm[t] = fmaxf(sqrtf(Sred[b * 1088 + 1024 + t]), 1e-12f);
    __syncthreads();

    if (t < 32) {
        const float T = temp[0];
        const float qn = snorm[32 + t];
        float m = -1e30f;
        for (int d = 0; d < 32; ++d)
            m = fmaxf(m, sS[t * 32 + d] / (qn * snorm[d]) * T);
        float sum = 0.f;
        for (int d = 0; d < 32; ++d)
            sum += expf(sS[t * 32 + d] / (qn * snorm[d]) * T - m);
        const float inv = 1.f / sum;
        for (int d = 0; d < 32; ++d)
            sA[t * 32 + d] = expf(sS[t * 32 + d] / (qn * snorm[d]) * T - m) * inv;
    }
    __syncthreads();

    for (int idx = t; idx < CO * CIN; idx += 256) {
        int cc = idx >> 7;
        int ci = idx & 127;
        float s = 0.f;
#pragma unroll
        for (int d = 0; d < 32; ++d) s += sA[cc * 32 + d] * w_v[d * CIN + ci];
        Weff[(size_t)b * CO * CIN + idx] = s;
    }
    if (t < 32) {
        float s = 0.f;
#pragma unroll
        for (int d = 0; d < 32; ++d) s += sA[t * 32 + d] * b_v[d];
        beff[b * CO + t] = s;
    }
}

// ---------------------------------------------------------------------------
// Kernel C — EXACT R3 out v1 (single launch).
// ---------------------------------------------------------------------------
__global__ __launch_bounds__(256) void out_kernel(const float* __restrict__ x,
                                                  const float* __restrict__ Weff,
                                                  const float* __restrict__ beff,
                                                  float* __restrict__ out) {
    const int b = blockIdx.y;
    const int n0 = blockIdx.x * 512 + threadIdx.x * 2;
    const float* xb = x + (size_t)b * CIN * NN + n0;
    const float* Wb = Weff + (size_t)b * CO * CIN;
    const float* bb = beff + b * CO;

    float a0[CO], a1[CO];
#pragma unroll
    for (int o = 0; o < CO; ++o) { a0[o] = bb[o]; a1[o] = bb[o]; }

#pragma unroll 4
    for (int ci = 0; ci < CIN; ++ci) {
        float2 xv = *(const float2*)(xb + (size_t)ci * NN);
#pragma unroll
        for (int o = 0; o < CO; ++o) {
            float wv = Wb[o * CIN + ci];
            a0[o] = fmaf(wv, xv.x, a0[o]);
            a1[o] = fmaf(wv, xv.y, a1[o]);
        }
    }

    float* ob = out + (size_t)b * CO * NN + n0;
#pragma unroll
    for (int o = 0; o < CO; ++o) {
        float2 r;
        r.x = a0[o];
        r.y = a1[o];
        *(float2*)(ob + (size_t)o * NN) = r;
    }
}

// ---------------------------------------------------------------------------
extern "C" void kernel_launch(void* const* d_in, const int* in_sizes, int n_in,
                              void* d_out, int out_size, void* d_ws, size_t ws_size,
                              hipStream_t stream) {
    const float* x    = (const float*)d_in[0];
    const float* qk   = (const float*)d_in[1];
    const float* w_v  = (const float*)d_in[2];
    const float* b_v  = (const float*)d_in[3];
    const float* temp = (const float*)d_in[4];
    float* out = (float*)d_out;

    float* part   = (float*)d_ws;                       // NB*GBLK*1024 floats (2 MB)
    float* partsq = part + (size_t)NB * GBLK * 1024;    // NB*GBLK*64 floats
    float* Sred   = partsq + (size_t)NB * GBLK * 64;    // NB*1088 floats
    float* Weff   = Sred + (size_t)NB * 1088;           // NB*CO*CIN floats
    float* beff   = Weff + (size_t)NB * CO * CIN;       // NB*CO floats

    gram_kernel<<<dim3(GBLK, NB), 256, 0, stream>>>(qk, part, partsq);
    reduce_kernel<<<dim3(17, NB), 128, 0, stream>>>(part, partsq, Sred);
    attn_kernel<<<dim3(NB), 256, 0, stream>>>(Sred, w_v, b_v, temp, Weff, beff);
    out_kernel<<<dim3(NN / 512, NB), 256, 0, stream>>>(x, Weff, beff, out);
}

// Round 9
// 116.508 us; speedup vs baseline: 2.2050x; 1.0413x over previous
//
#include <hip/hip_runtime.h>
#include <hip/hip_bf16.h>
#include <math.h>

// Problem constants (fixed shapes from setup_inputs)
#define NB    8
#define CIN   128
#define CO    32
#define CH    64            // 2*Co channels in qk
#define NN    65536         // H*W
#define CPB   512           // columns per gram block
#define GBLK  (NN/CPB)      // 128 gram blocks per batch
#define TCOLS 128           // columns per LDS tile
#define NTILES (CPB/TCOLS)  // 4 tiles per block

typedef __attribute__((ext_vector_type(8))) short bf16x8;
typedef __attribute__((ext_vector_type(16))) float f32x16;

__device__ __forceinline__ short f2bf(float f) {
    union { __hip_bfloat16 h; short s; } u;
    u.h = __float2bfloat16(f);
    return u.s;
}
__device__ __forceinline__ float bf2f(short s) {
    union { __hip_bfloat16 h; short s; } u;
    u.s = s;
    return __bfloat162float(u.h);
}

// ---------------------------------------------------------------------------
// Kernel A v6 — v5 structure + register-staged double-buffer + 4 blocks/CU.
// Block = 512 cols (4 tiles of 128). Per tile: write staged regs -> swizzled
// LDS, barrier, ISSUE next tile's 8 global loads (in flight during compute),
// compute MFMAs from LDS, barrier. 32x32x16 bf16 MFMA hi/lo split.
//   part[b][blk][q*32+k], partsq[b][blk][ch] (0..31=k, 32..63=q)
// ---------------------------------------------------------------------------
__global__ __launch_bounds__(256) void gram_kernel(const float* __restrict__ qk,
                                                   float* __restrict__ part,
                                                   float* __restrict__ partsq) {
    __shared__ float smem[CH * TCOLS];   // 32 KB; reused for epilogue reduce
    float4* tile4 = (float4*)smem;       // [64][32] float4 view

    const int b = blockIdx.y;
    const int blk = blockIdx.x;
    const int t = threadIdx.x;
    const int w = t >> 6;
    const int l = t & 63;
    const int c = l & 31;       // channel within the 32-set
    const int half = l >> 5;    // k-half selector

    const float* qkb = qk + (size_t)b * CH * NN;
    const size_t colbase0 = (size_t)blk * CPB;

    // per-thread load coordinates (fixed across tiles)
    const int lrow[8] = {  (t) >> 5, (t + 256) >> 5, (t + 512) >> 5, (t + 768) >> 5,
                           (t + 1024) >> 5, (t + 1280) >> 5, (t + 1536) >> 5, (t + 1792) >> 5 };
    const int lcol4 = t & 31;

    f32x16 acc = {};
    float sq[8] = {0.f, 0.f, 0.f, 0.f, 0.f, 0.f, 0.f, 0.f};

    // ---- preload tile 0 into registers
    float4 st[8];
#pragma unroll
    for (int k = 0; k < 8; ++k)
        st[k] = *(const float4*)(qkb + (size_t)lrow[k] * NN + colbase0 + lcol4 * 4);

#pragma unroll
    for (int tau = 0; tau < NTILES; ++tau) {
        // ---- drain staged regs into swizzled LDS (+ square-sums)
#pragma unroll
        for (int k = 0; k < 8; ++k) {
            float4 v = st[k];
            sq[k] = fmaf(v.x, v.x, sq[k]);
            sq[k] = fmaf(v.y, v.y, sq[k]);
            sq[k] = fmaf(v.z, v.z, sq[k]);
            sq[k] = fmaf(v.w, v.w, sq[k]);
            tile4[lrow[k] * 32 + (lcol4 ^ (lrow[k] & 7))] = v;
        }
        __syncthreads();

        // ---- issue next tile's loads (in flight during compute below)
        if (tau + 1 < NTILES) {
            const size_t colbase = colbase0 + (size_t)(tau + 1) * TCOLS;
#pragma unroll
            for (int k = 0; k < 8; ++k)
                st[k] = *(const float4*)(qkb + (size_t)lrow[k] * NN + colbase + lcol4 * 4);
        }

        // ---- compute: wave w -> sub-slices s = 2w, 2w+1 (16 cols each)
#pragma unroll
        for (int ss = 0; ss < 2; ++ss) {
            const int s = 2 * w + ss;
            const int f0 = s * 4 + half * 2;
            const int qrow = CO + c;
            const int krow = c;
            const int sw = c & 7;    // (32+c)&7 == c&7
            float4 q0 = tile4[qrow * 32 + (f0 ^ sw)];
            float4 q1 = tile4[qrow * 32 + ((f0 + 1) ^ sw)];
            float4 k0 = tile4[krow * 32 + (f0 ^ sw)];
            float4 k1 = tile4[krow * 32 + ((f0 + 1) ^ sw)];

            float qf[8] = {q0.x, q0.y, q0.z, q0.w, q1.x, q1.y, q1.z, q1.w};
            float kf[8] = {k0.x, k0.y, k0.z, k0.w, k1.x, k1.y, k1.z, k1.w};

            bf16x8 ah, al, bh, bl;
#pragma unroll
            for (int j = 0; j < 8; ++j) {
                short hq = f2bf(qf[j]);
                ah[j] = hq;
                al[j] = f2bf(qf[j] - bf2f(hq));
                short hk = f2bf(kf[j]);
                bh[j] = hk;
                bl[j] = f2bf(kf[j] - bf2f(hk));
            }
            acc = __builtin_amdgcn_mfma_f32_32x32x16_bf16(ah, bh, acc, 0, 0, 0);
            acc = __builtin_amdgcn_mfma_f32_32x32x16_bf16(ah, bl, acc, 0, 0, 0);
            acc = __builtin_amdgcn_mfma_f32_32x32x16_bf16(al, bh, acc, 0, 0, 0);
        }
        __syncthreads();   // all LDS reads done before next tile's writes
    }

    // ---- stage per-wave acc: C/D layout col = lane&31 (k idx),
    //      row = (r&3) + 8*(r>>2) + 4*half (q idx)
#pragma unroll
    for (int r = 0; r < 16; ++r) {
        int row = (r & 3) + 8 * (r >> 2) + 4 * half;
        smem[w * 1024 + row * 32 + c] = acc[r];
    }
    // ---- stage per-thread square-sums: row = (t>>5)+8k, slot = t&31
#pragma unroll
    for (int k = 0; k < 8; ++k)
        smem[4096 + ((t >> 5) + 8 * k) * 32 + (t & 31)] = sq[k];
    __syncthreads();

    float* pp = part + ((size_t)b * GBLK + blk) * 1024;
#pragma unroll
    for (int j = 0; j < 4; ++j) {
        int idx = t + j * 256;
        pp[idx] = smem[idx] + smem[1024 + idx] + smem[2048 + idx] + smem[3072 + idx];
    }
    if (t < 64) {
        float s = 0.f;
#pragma unroll
        for (int i = 0; i < 32; ++i) s += smem[4096 + t * 32 + i];
        partsq[((size_t)b * GBLK + blk) * 64 + t] = s;
    }
}

// ---------------------------------------------------------------------------
// Kernel B1: reduce partials over 128 chunks -> Sred[b][0..1023]=S, [1024..1087]=sumsq
// ---------------------------------------------------------------------------
__global__ __launch_bounds__(128) void reduce_kernel(const float* __restrict__ part,
                                                     const float* __restrict__ partsq,
                                                     float* __restrict__ Sred) {
    const int b = blockIdx.y;
    const int v = blockIdx.x * 64 + (threadIdx.x >> 1);
    const int h = threadIdx.x & 1;
    float s = 0.f;
    if (v < 1024) {
        const float* p = part + (size_t)b * GBLK * 1024 + v;
        for (int ch = h * (GBLK / 2); ch < (h + 1) * (GBLK / 2); ++ch)
            s += p[(size_t)ch * 1024];
    } else {
        const float* p = partsq + (size_t)b * GBLK * 64 + (v - 1024);
        for (int ch = h * (GBLK / 2); ch < (h + 1) * (GBLK / 2); ++ch)
            s += p[(size_t)ch * 64];
    }
    s += __shfl_xor(s, 1);
    if (h == 0) Sred[b * 1088 + v] = s;
}

// ---------------------------------------------------------------------------
// Kernel B2 — EXACT R3 attn_kernel
// ---------------------------------------------------------------------------
__global__ __launch_bounds__(256) void attn_kernel(const float* __restrict__ Sred,
                                                   const float* __restrict__ w_v,
                                                   const float* __restrict__ b_v,
                                                   const float* __restrict__ temp,
                                                   float* __restrict__ Weff,
                                                   float* __restrict__ beff) {
    __shared__ float sS[1024];
    __shared__ float snorm[64];
    __shared__ float sA[1024];
    const int t = threadIdx.x;
    const int b = blockIdx.x;

    for (int i = t; i < 1024; i += 256) sS[i] = Sred[b * 1088 + i];
    if (t < 64) snorm[t] = fmaxf(sqrtf(Sred[b * 1088 + 1024 + t]), 1e-12f);
    __syncthreads();

    if (t < 32) {
        const float T = temp[0];
        const float qn = snorm[32 + t];
        float m = -1e30f;
        for (int d = 0; d < 32; ++d)
            m = fmaxf(m, sS[t * 32 + d] / (qn * snorm[d]) * T);
        float sum = 0.f;
        for (int d = 0; d < 32; ++d)
            sum += expf(sS[t * 32 + d] / (qn * snorm[d]) * T - m);
        const float inv = 1.f / sum;
        for (int d = 0; d < 32; ++d)
            sA[t * 32 + d] = expf(sS[t * 32 + d] / (qn * snorm[d]) * T - m) * inv;
    }
    __syncthreads();

    for (int idx = t; idx < CO * CIN; idx += 256) {
        int cc = idx >> 7;
        int ci = idx & 127;
        float s = 0.f;
#pragma unroll
        for (int d = 0; d < 32; ++d) s += sA[cc * 32 + d] * w_v[d * CIN + ci];
        Weff[(size_t)b * CO * CIN + idx] = s;
    }
    if (t < 32) {
        float s = 0.f;
#pragma unroll
        for (int d = 0; d < 32; ++d) s += sA[t * 32 + d] * b_v[d];
        beff[b * CO + t] = s;
    }
}

// ---------------------------------------------------------------------------
// Kernel C — EXACT R3 out v1 (single launch).
// ---------------------------------------------------------------------------
__global__ __launch_bounds__(256) void out_kernel(const float* __restrict__ x,
                                                  const float* __restrict__ Weff,
                                                  const float* __restrict__ beff,
                                                  float* __restrict__ out) {
    const int b = blockIdx.y;
    const int n0 = blockIdx.x * 512 + threadIdx.x * 2;
    const float* xb = x + (size_t)b * CIN * NN + n0;
    const float* Wb = Weff + (size_t)b * CO * CIN;
    const float* bb = beff + b * CO;

    float a0[CO], a1[CO];
#pragma unroll
    for (int o = 0; o < CO; ++o) { a0[o] = bb[o]; a1[o] = bb[o]; }

#pragma unroll 4
    for (int ci = 0; ci < CIN; ++ci) {
        float2 xv = *(const float2*)(xb + (size_t)ci * NN);
#pragma unroll
        for (int o = 0; o < CO; ++o) {
            float wv = Wb[o * CIN + ci];
            a0[o] = fmaf(wv, xv.x, a0[o]);
            a1[o] = fmaf(wv, xv.y, a1[o]);
        }
    }

    float* ob = out + (size_t)b * CO * NN + n0;
#pragma unroll
    for (int o = 0; o < CO; ++o) {
        float2 r;
        r.x = a0[o];
        r.y = a1[o];
        *(float2*)(ob + (size_t)o * NN) = r;
    }
}

// ---------------------------------------------------------------------------
extern "C" void kernel_launch(void* const* d_in, const int* in_sizes, int n_in,
                              void* d_out, int out_size, void* d_ws, size_t ws_size,
                              hipStream_t stream) {
    const float* x    = (const float*)d_in[0];
    const float* qk   = (const float*)d_in[1];
    const float* w_v  = (const float*)d_in[2];
    const float* b_v  = (const float*)d_in[3];
    const float* temp = (const float*)d_in[4];
    float* out = (float*)d_out;

    float* part   = (float*)d_ws;                       // NB*GBLK*1024 floats (4 MB)
    float* partsq = part + (size_t)NB * GBLK * 1024;    // NB*GBLK*64 floats
    float* Sred   = partsq + (size_t)NB * GBLK * 64;    // NB*1088 floats
    float* Weff   = Sred + (size_t)NB * 1088;           // NB*CO*CIN floats
    float* beff   = Weff + (size_t)NB * CO * CIN;       // NB*CO floats

    gram_kernel<<<dim3(GBLK, NB), 256, 0, stream>>>(qk, part, partsq);
    reduce_kernel<<<dim3(17, NB), 128, 0, stream>>>(part, partsq, Sred);
    attn_kernel<<<dim3(NB), 256, 0, stream>>>(Sred, w_v, b_v, temp, Weff, beff);
    out_kernel<<<dim3(NN / 512, NB), 256, 0, stream>>>(x, Weff, beff, out);
}